// Round 6
// baseline (269.055 us; speedup 1.0000x reference)
//
#include <hip/hip_runtime.h>
#include <stdint.h>

#define B_      32
#define T_IN_   512
#define N_      543
#define C_      3
#define NEW_T_  426     // int(512/1.2)
#define JF_     53      // max(1, 426//8)
#define NC_     (N_*C_)             // 1629
#define XOUT_   (B_*NEW_T_*NC_)     // 22206528
#define GPF_    408                 // groups per frame: ceil(1629/4)
#define FPB_    6                   // frames per block strip
#define NTB_    71                  // 426 / 6, exact
#define NBLKM_  (NTB_*B_)           // 2272 = 8 * 284 exactly
#define CPX_    284                 // blocks per XCD chunk (bijective)
#define WROWS_  9                   // staged x window rows per block
#define LROW_   1632                // padded LDS row (floats): 6528 B, 16B-aligned

#define MODE_INT   0
#define MODE_BYTE  1
#define MODE_FLOAT 2

// global-side 16B vector, 4-byte alignment (frame stride 1629 floats is odd)
typedef float f4u __attribute__((vector_size(16), aligned(4)));
// LDS-side 16B vector, natural 16B alignment -> clean ds_read_b128
typedef float f4a __attribute__((vector_size(16)));

__device__ __forceinline__ f4u lds_ld(const float* p) {
    f4a t = *(const f4a*)p;
    f4u r; r[0]=t[0]; r[1]=t[1]; r[2]=t[2]; r[3]=t[3];
    return r;
}
__device__ __forceinline__ void lds_st(float* p, f4u v) {
    f4a t; t[0]=v[0]; t[1]=v[1]; t[2]=v[2]; t[3]=v[3];
    *(f4a*)p = t;
}

__device__ __forceinline__ bool read_flag(const void* p, int mode, int idx) {
    if (mode == MODE_BYTE)  return ((const uint8_t*)p)[idx] != 0;
    if (mode == MODE_FLOAT) return ((const float*)p)[idx]   != 0.0f;
    return ((const int*)p)[idx] != 0;
}

// Fused kernel: one block per (batch b, strip of FPB_=6 frames), XCD-swizzled.
//  - prep fused in: per-block 426-elem keep-scan (LDS, ~1us, hides under the
//    early global loads) + per-block metadata for its 7 frames + mask write.
//  - x window rows [i0(t0) .. i0(t0)+8] staged via regs into LDS (58.7 KB):
//    kept-frame taps are in-window by construction; dropped/prologue taps fall
//    back to global (block-uniform branch, ~10%). Cuts lane-level x service
//    traffic ~255 -> ~165 MB and moves tap re-reads onto the LDS pipe.
//  - element 1628 of each frame handled by a scalar tail pass (thread 407) so
//    all LDS vector accesses are 16B-aligned ds_read_b128/ds_write_b128.
//  - R5 keepers: XCD swizzle, regular (cached) stores, nt noise loads,
//    register-carried ap, wave-uniform skip of zero-weight taps.
__global__ __launch_bounds__(448) __attribute__((amdgpu_waves_per_eu(3, 8)))
void fused_kernel(
    const float* __restrict__ x,
    const void*  __restrict__ maskp,
    const void*  __restrict__ keepp,
    const float* __restrict__ bjit,
    const float* __restrict__ noise,
    const float* __restrict__ spat,
    float* __restrict__ out,
    float* __restrict__ out_mask)
{
    const int j = threadIdx.x;
    const uint32_t bid = blockIdx.x;
    const uint32_t swz = (bid & 7u) * (uint32_t)CPX_ + (bid >> 3);
    const int b  = (int)(swz / (uint32_t)NTB_);
    const int t0 = (int)(swz % (uint32_t)NTB_) * FPB_;
    const int bt0 = b * NEW_T_ + t0;

    __shared__ __align__(16) float sx[WROWS_ * LROW_];   // 58752 B
    __shared__ int   ps[448];
    __shared__ int   kept[NEW_T_];
    __shared__ int   flags[6];
    __shared__ int   s_modes[2];
    __shared__ int4  smF[8];        // slots 0..5 frames, 6 = prologue
    __shared__ float4 smW[8];
    __shared__ float smJ[8];

    const float RATX = (float)(511.0 / 425.0);
    int row_base = (int)floorf((float)t0 * RATX);
    if (row_base < 0) row_base = 0;
    const float* __restrict__ xb = x + (size_t)b * (T_IN_ * NC_);

    // vector-path element offset (16B-aligned in LDS): covers floats 0..1627;
    // float 1628 is done by the scalar tail pass on thread 407.
    uint32_t e0v = (uint32_t)j * 4u;
    if (e0v > 1624u) e0v = 1624u;               // thread 407 dups thread 406 (identical writes)

    // ---- early VMEM: stage window rows into regs + nz + sp (all in flight) ----
    f4u st[WROWS_]; float st_last[WROWS_];
    #pragma unroll
    for (int r = 0; r < WROWS_; ++r) {
        int rr = row_base + r; if (rr > T_IN_ - 1) rr = T_IN_ - 1;   // dup-stage clamp, never read for taps
        const float* src = xb + (size_t)rr * NC_;
        if (j < 407)       st[r] = *(const f4u*)(src + j * 4);
        else if (j == 407) st_last[r] = src[1628];
    }
    f4u nz[FPB_];
    #pragma unroll
    for (int i = 0; i < FPB_; ++i)
        nz[i] = __builtin_nontemporal_load((const f4u*)(noise + (size_t)(bt0 + i) * NC_ + e0v));
    const f4u sp = *(const f4u*)(spat + (size_t)b * NC_ + e0v);

    // ---- mode detection (same heuristic as before) ----
    if (j < 6) flags[j] = 0;
    __syncthreads();
    if (j < 64) {
        uint32_t vm = ((const uint32_t*)maskp)[j];
        uint32_t vk = ((const uint32_t*)keepp)[j];
        if (vm == 0x3F800000u)      atomicOr(&flags[2], 1);
        else if (vm > 1u)           atomicOr(&flags[1], 1);
        if (vk == 0x3F800000u)      atomicOr(&flags[5], 1);
        else if (vk > 1u)           atomicOr(&flags[4], 1);
    }
    __syncthreads();
    if (j == 0) {
        s_modes[0] = flags[2] ? MODE_FLOAT : (flags[1] ? MODE_BYTE : MODE_INT);
        s_modes[1] = flags[5] ? MODE_FLOAT : (flags[4] ? MODE_BYTE : MODE_INT);
    }
    __syncthreads();
    const int mmode = s_modes[0], kmode = s_modes[1];

    // ---- optimistic prologue (prev frame kept ~90%): issue q loads early ----
    const int tp = t0 ? t0 - 1 : 0;
    const int pk = read_flag(keepp, kmode, b * NEW_T_ + tp) ? 1 : 0;
    float stp = (float)tp * RATX;
    int p0 = (int)floorf(stp);
    if (p0 < 0) p0 = 0; if (p0 > T_IN_ - 2) p0 = T_IN_ - 2;
    const float wp = stp - (float)p0;
    f4u q0g, q1g;
    if (pk) {
        q0g = *(const f4u*)(xb + (uint32_t)p0 * NC_ + e0v);
        q1g = *(const f4u*)(xb + (uint32_t)(p0 + 1) * NC_ + e0v);
    }

    // ---- keep-flag scan: 448-thread Hillis-Steele over 426 ----
    int kv = 0;
    if (j < NEW_T_) kv = read_flag(keepp, kmode, b * NEW_T_ + j) ? 1 : 0;
    ps[j] = kv;
    __syncthreads();
    #pragma unroll
    for (int off = 1; off < 448; off <<= 1) {
        int v = (j >= off) ? ps[j - off] : 0;
        __syncthreads();
        ps[j] += v;
        __syncthreads();
    }
    const int K = ps[NEW_T_ - 1];
    if (j < NEW_T_ && kv) kept[ps[j] - 1] = j;
    __syncthreads();

    // ---- commit staged rows to LDS (16B-aligned ds_write_b128) ----
    #pragma unroll
    for (int r = 0; r < WROWS_; ++r) {
        if (j < 407)       lds_st(&sx[r * LROW_ + j * 4], st[r]);
        else if (j == 407) sx[r * LROW_ + 1628] = st_last[r];
    }

    // ---- metadata: threads 0..6 compute per-frame F/W/J; threads 0..5 write mask ----
    if (j < 7) {
        const int t = (j < 6) ? (t0 + j) : tp;
        const int kvt = read_flag(keepp, kmode, b * NEW_T_ + t) ? 1 : 0;
        float stx = (float)t * RATX;
        int i0 = (int)floorf(stx);
        if (i0 < 0) i0 = 0; if (i0 > T_IN_ - 2) i0 = T_IN_ - 2;
        float w = stx - (float)i0;
        int4 F; float4 W;
        if (kvt) {
            F = make_int4(i0, i0 + 1, i0, i0 + 1);
            W = make_float4(1.0f - w, w, 0.0f, 0.0f);
        } else {
            float s = ((float)t * (float)(K - 1)) / 425.0f;
            int r0 = (int)floorf(s);
            if (r0 < 0) r0 = 0; if (r0 > K - 2) r0 = K - 2;
            float f = s - (float)r0;
            int j0 = kept[r0], j1 = kept[r0 + 1];
            float s0 = (float)j0 * RATX;
            int a0 = (int)floorf(s0);
            if (a0 < 0) a0 = 0; if (a0 > T_IN_ - 2) a0 = T_IN_ - 2;
            float w0 = s0 - (float)a0;
            float s1 = (float)j1 * RATX;
            int a1 = (int)floorf(s1);
            if (a1 < 0) a1 = 0; if (a1 > T_IN_ - 2) a1 = T_IN_ - 2;
            float w1 = s1 - (float)a1;
            F = make_int4(a0, a0 + 1, a1, a1 + 1);
            W = make_float4((1.0f - f) * (1.0f - w0), (1.0f - f) * w0,
                            f * (1.0f - w1),          f * w1);
        }
        smF[j] = F; smW[j] = W;
        if (j < 6) {
            const float RATJ = (float)(52.0 / 425.0);
            float sj = (float)t * RATJ;
            int ji = (int)floorf(sj);
            if (ji < 0) ji = 0; if (ji > JF_ - 2) ji = JF_ - 2;
            float jf = sj - (float)ji;
            float b0 = bjit[b * JF_ + ji]     * 0.02f;
            float b1 = bjit[b * JF_ + ji + 1] * 0.02f;
            float jv2 = b0 * (1.0f - jf) + b1 * jf;
            if (t == 0) jv2 = 0.0f;
            smJ[j] = jv2;
            float mn = (float)t * (float)(512.0 / 426.0);
            int nidx = (int)floorf(mn);
            if (nidx > T_IN_ - 1) nidx = T_IN_ - 1;
            bool mo = read_flag(maskp, mmode, b * T_IN_ + nidx) && (kvt != 0);
            out_mask[b * NEW_T_ + t] = mo ? 1.0f : 0.0f;
        }
    }
    __syncthreads();

    // ---- compute: LDS taps (kept frames always in-window), global fallback ----
    if (j < GPF_) {
        f4u ap;
        if (pk) {
            ap = (1.0f - wp) * q0g + wp * q1g;          // bit-identical to smW[6] path
        } else {
            const int4 Fp = smF[6]; const float4 Wp = smW[6];
            f4u q0 = *(const f4u*)(xb + (uint32_t)Fp.x * NC_ + e0v);
            f4u q1 = *(const f4u*)(xb + (uint32_t)Fp.y * NC_ + e0v);
            ap = Wp.x * q0 + Wp.y * q1;
            if (Wp.z != 0.0f || Wp.w != 0.0f) {
                f4u q2 = *(const f4u*)(xb + (uint32_t)Fp.z * NC_ + e0v);
                f4u q3 = *(const f4u*)(xb + (uint32_t)Fp.w * NC_ + e0v);
                ap += Wp.z * q2 + Wp.w * q3;
            }
        }
        #pragma unroll
        for (int i = 0; i < FPB_; ++i) {
            const int4 F = smF[i]; const float4 W = smW[i]; const float jvi = smJ[i];
            const int rlx = F.x - row_base;               // F.y == F.x+1 always
            f4u v0, v1;
            if ((unsigned)rlx < (unsigned)(WROWS_ - 1)) { // both rows staged
                v0 = lds_ld(&sx[rlx * LROW_ + e0v]);
                v1 = lds_ld(&sx[(rlx + 1) * LROW_ + e0v]);
            } else {
                v0 = *(const f4u*)(xb + (uint32_t)F.x * NC_ + e0v);
                v1 = *(const f4u*)(xb + (uint32_t)F.y * NC_ + e0v);
            }
            f4u a = W.x * v0 + W.y * v1;
            if (W.z != 0.0f || W.w != 0.0f) {             // dropped frames only (~10%)
                const int rlz = F.z - row_base;
                f4u v2, v3;
                if ((unsigned)rlz < (unsigned)(WROWS_ - 1)) {
                    v2 = lds_ld(&sx[rlz * LROW_ + e0v]);
                    v3 = lds_ld(&sx[(rlz + 1) * LROW_ + e0v]);
                } else {
                    v2 = *(const f4u*)(xb + (uint32_t)F.z * NC_ + e0v);
                    v3 = *(const f4u*)(xb + (uint32_t)F.w * NC_ + e0v);
                }
                a += W.z * v2 + W.w * v3;
            }
            f4u r = a + (a - ap) * jvi + nz[i] * 0.01f + sp * 0.005f;
            *(f4u*)(out + (size_t)(bt0 + i) * NC_ + e0v) = r;
            ap = a;
        }

        // ---- scalar tail: element 1628 of each frame (thread 407 only) ----
        if (j == 407) {
            const int4 Fp2 = smF[6]; const float4 Wp2 = smW[6];
            float aps = Wp2.x * xb[(uint32_t)Fp2.x * NC_ + 1628]
                      + Wp2.y * xb[(uint32_t)Fp2.y * NC_ + 1628];
            if (Wp2.z != 0.0f || Wp2.w != 0.0f)
                aps += Wp2.z * xb[(uint32_t)Fp2.z * NC_ + 1628]
                     + Wp2.w * xb[(uint32_t)Fp2.w * NC_ + 1628];
            const float sps = spat[(size_t)b * NC_ + 1628];
            #pragma unroll
            for (int i = 0; i < FPB_; ++i) {
                const int4 F = smF[i]; const float4 W = smW[i];
                const int rlx = F.x - row_base;
                float v0s, v1s;
                if ((unsigned)rlx < (unsigned)(WROWS_ - 1)) {
                    v0s = sx[rlx * LROW_ + 1628]; v1s = sx[(rlx + 1) * LROW_ + 1628];
                } else {
                    v0s = xb[(uint32_t)F.x * NC_ + 1628]; v1s = xb[(uint32_t)F.y * NC_ + 1628];
                }
                float as = W.x * v0s + W.y * v1s;
                if (W.z != 0.0f || W.w != 0.0f) {
                    const int rlz = F.z - row_base;
                    float v2s, v3s;
                    if ((unsigned)rlz < (unsigned)(WROWS_ - 1)) {
                        v2s = sx[rlz * LROW_ + 1628]; v3s = sx[(rlz + 1) * LROW_ + 1628];
                    } else {
                        v2s = xb[(uint32_t)F.z * NC_ + 1628]; v3s = xb[(uint32_t)F.w * NC_ + 1628];
                    }
                    as += W.z * v2s + W.w * v3s;
                }
                float nzs = noise[(size_t)(bt0 + i) * NC_ + 1628];
                float rs = as + (as - aps) * smJ[i] + nzs * 0.01f + sps * 0.005f;
                out[(size_t)(bt0 + i) * NC_ + 1628] = rs;
                aps = as;
            }
        }
    }
}

extern "C" void kernel_launch(void* const* d_in, const int* in_sizes, int n_in,
                              void* d_out, int out_size, void* d_ws, size_t ws_size,
                              hipStream_t stream) {
    const float* x    = (const float*)d_in[0];
    const void*  mask = d_in[1];
    const void*  keep = d_in[2];
    const float* bjit = (const float*)d_in[3];
    const float* noise = (const float*)d_in[4];
    const float* spat  = (const float*)d_in[5];
    float* out = (float*)d_out;

    fused_kernel<<<NBLKM_, 448, 0, stream>>>(x, mask, keep, bjit, noise, spat,
                                             out, out + XOUT_);
}